// Round 1
// baseline (1184.360 us; speedup 1.0000x reference)
//
#include <hip/hip_runtime.h>
#include <math.h>

#define B_ 128
#define S_ 256
#define H_ 768
#define K_ 6

// ---- out layout (floats) ----
// logits @0 (128) | z_base @128 (128*3846) | router_w @492416 (768) |
// router_logits @493184 (768) | expert_aux @493952 (768)
#define OUT_ZB 128
#define OUT_RW 492416
#define OUT_RL 493184
#define OUT_AUX 493952

// ---- ws layout (float offsets) ----
#define OFF_SMW   0
#define OFF_TB    16
#define OFF_LB    1040
#define OFF_CNT   2064
#define OFF_UACC  4096
#define OFF_VACC  102400
#define OFF_ALPHA 200704
#define OFF_POOLED 397312
#define OFF_H1    987136
#define OFF_Z     1576960
#define OFF_RIN   1970176
#define OFF_RH    2474752
#define OFF_RWW   2540288
#define OFF_C     2541056
#define OFF_C1    3426560
#define OFF_C2    3557632

__device__ __forceinline__ float gelu_f(float x){
  return 0.5f*x*(1.f+erff(x*0.7071067811865475f));
}
__device__ __forceinline__ float wave_red_sum(float v){
  #pragma unroll
  for (int o=32;o;o>>=1) v += __shfl_down(v,o);
  return v;
}
__device__ __forceinline__ float block_red_sum(float v, float* sh){
  v = wave_red_sum(v);
  if ((threadIdx.x&63)==0) sh[threadIdx.x>>6]=v;
  __syncthreads();
  v = sh[0]+sh[1]+sh[2]+sh[3];
  __syncthreads();
  return v;
}
__device__ __forceinline__ float block_red_max(float v, float* sh){
  #pragma unroll
  for (int o=32;o;o>>=1) v = fmaxf(v,__shfl_down(v,o));
  if ((threadIdx.x&63)==0) sh[threadIdx.x>>6]=v;
  __syncthreads();
  v = fmaxf(fmaxf(sh[0],sh[1]),fmaxf(sh[2],sh[3]));
  __syncthreads();
  return v;
}

// ---------- masks + layer softmax ----------
__global__ void k_prep(const int* __restrict__ ids, const int* __restrict__ am,
                       const float* __restrict__ lw, float* __restrict__ ws)
{
  int b = blockIdx.x, t = threadIdx.x;
  __shared__ unsigned long long shsep[4];
  __shared__ int shi[4];
  int amsum = 0;
  #pragma unroll
  for (int j=0;j<4;++j){
    int s = t + 64*j;
    int id = ids[b*S_+s];
    amsum += am[b*S_+s];
    unsigned long long bal = __ballot(id==2);
    if (t==0) shsep[j] = bal;
  }
  #pragma unroll
  for (int o=32;o;o>>=1) amsum += __shfl_down(amsum,o);
  if (t==0){
    int nsep=0, s1=S_, s2=S_;
    for (int j=0;j<4;++j){
      unsigned long long m = shsep[j];
      while (m){
        int bit = __ffsll(m)-1;
        m &= m-1; nsep++;
        int pos = j*64+bit;
        if (nsep==1) s1=pos; else if (nsep==2) s2=pos;
      }
    }
    shi[0]=s1; shi[1]=s2; shi[2]=nsep; shi[3]=amsum;
  }
  __syncthreads();
  int s1=shi[0], s2=shi[1], nsep=shi[2], vlen=shi[3];
  int endp = min(vlen-1, S_);
  bool has2 = (nsep>=2);
  unsigned int* tb = (unsigned int*)(ws + OFF_TB);
  unsigned int* lb = (unsigned int*)(ws + OFF_LB);
  int cntt=0, cntl=0;
  #pragma unroll
  for (int j=0;j<4;++j){
    int s = t + 64*j;
    bool fb = (vlen>2) ? (s>=1 && s < vlen-1) : (s==0);
    bool tm_ = has2 ? (s>=1 && s<s1) : fb;
    bool lm_ = has2 ? (s>=s2+1 && s<endp) : fb;
    unsigned long long bt = __ballot(tm_);
    unsigned long long bl = __ballot(lm_);
    if (t==0){
      tb[b*8+2*j]   = (unsigned)(bt & 0xffffffffull);
      tb[b*8+2*j+1] = (unsigned)(bt>>32);
      lb[b*8+2*j]   = (unsigned)(bl & 0xffffffffull);
      lb[b*8+2*j+1] = (unsigned)(bl>>32);
      cntt += __popcll(bt); cntl += __popcll(bl);
    }
  }
  if (t==0){ ws[OFF_CNT+b*2] = (float)cntt; ws[OFF_CNT+b*2+1] = (float)cntl; }
  if (b==0 && t==0){
    float w0=lw[0],w1=lw[1],w2=lw[2],w3=lw[3];
    float m = fmaxf(fmaxf(w0,w1),fmaxf(w2,w3));
    float e0=expf(w0-m),e1=expf(w1-m),e2=expf(w2-m),e3=expf(w3-m);
    float s = e0+e1+e2+e3;
    ws[OFF_SMW+0]=e0/s; ws[OFF_SMW+1]=e1/s; ws[OFF_SMW+2]=e2/s; ws[OFF_SMW+3]=e3/s;
  }
}

// ---------- fused wh + masked pooling (partial sums) ----------
__global__ __launch_bounds__(256) void k_pool(const float* __restrict__ h4, float* __restrict__ ws)
{
  int hc = blockIdx.x, q = blockIdx.y, b = blockIdx.z;
  int l = q >> 2, sc = q & 3;
  int h = hc*256 + threadIdx.x;
  const unsigned* tb = (const unsigned*)(ws + OFF_TB) + b*8 + sc*2;
  const unsigned* lb = (const unsigned*)(ws + OFF_LB) + b*8 + sc*2;
  unsigned t0 = tb[0], t1 = tb[1], l0 = lb[0], l1 = lb[1];
  float w = ws[OFF_SMW + l];
  const float* base = h4 + (((long)l*B_ + b)*S_ + sc*64)*H_ + h;
  float at=0.f, al=0.f;
  #pragma unroll 8
  for (int si=0; si<64; ++si){
    float x = base[(long)si*H_];
    unsigned bt = (si<32) ? (t0>>si) : (t1>>(si-32));
    unsigned bl = (si<32) ? (l0>>si) : (l1>>(si-32));
    if (bt & 1u) at += x;
    if (bl & 1u) al += x;
  }
  atomicAdd(ws + OFF_UACC + b*H_ + h, w*at);
  atomicAdd(ws + OFF_VACC + b*H_ + h, w*al);
}

// ---------- z_base ----------
__global__ void k_zbase(const float* __restrict__ ws, float* __restrict__ out,
                        const float* __restrict__ lh, const float* __restrict__ pt)
{
  int b = blockIdx.x, h = threadIdx.x;
  float cntt = ws[OFF_CNT+b*2], cntl = ws[OFF_CNT+b*2+1];
  float u = cntt>0.f ? ws[OFF_UACC+b*H_+h]/fmaxf(cntt,1.f) : 0.f;
  float v = cntl>0.f ? ws[OFF_VACC+b*H_+h]/fmaxf(cntl,1.f) : 0.f;
  float* zb = out + OUT_ZB + (long)b*3846;
  zb[h]       = lh[(long)b*S_*H_ + h];
  zb[768+h]   = u;
  zb[1536+h]  = v;
  zb[2304+h]  = fabsf(u-v);
  zb[3072+h]  = u*v;
  if (h<6) zb[3840+h] = pt[b*6+h];
}

// ---------- attention scores (wave per (b,s) row) ----------
__global__ __launch_bounds__(256) void k_scores(const float* __restrict__ lh,
    const float* __restrict__ aw_g, float* __restrict__ ws)
{
  __shared__ float aw[K_*H_];
  for (int i=threadIdx.x;i<K_*H_;i+=256) aw[i]=aw_g[i];
  __syncthreads();
  int row = blockIdx.x*4 + (threadIdx.x>>6);
  int lane = threadIdx.x & 63;
  const float* x = lh + (long)row*H_;
  float a0=0,a1=0,a2=0,a3=0,a4=0,a5=0;
  #pragma unroll
  for (int i=0;i<12;++i){
    int hh = lane + i*64;
    float xv = x[hh];
    a0 += xv*aw[hh];      a1 += xv*aw[768+hh];  a2 += xv*aw[1536+hh];
    a3 += xv*aw[2304+hh]; a4 += xv*aw[3072+hh]; a5 += xv*aw[3840+hh];
  }
  #pragma unroll
  for (int o=32;o;o>>=1){
    a0+=__shfl_down(a0,o); a1+=__shfl_down(a1,o); a2+=__shfl_down(a2,o);
    a3+=__shfl_down(a3,o); a4+=__shfl_down(a4,o); a5+=__shfl_down(a5,o);
  }
  if (lane==0){
    int b = row>>8, s = row&255;
    float* sc = ws + OFF_ALPHA + (long)b*K_*S_ + s;
    sc[0]=a0; sc[256]=a1; sc[512]=a2; sc[768]=a3; sc[1024]=a4; sc[1280]=a5;
  }
}

__global__ void k_softmax(float* __restrict__ ws, const float* __restrict__ ab,
                          const int* __restrict__ am)
{
  __shared__ float sh[4];
  int bk = blockIdx.x; int b = bk/K_, k = bk%K_; int s = threadIdx.x;
  float* row = ws + OFF_ALPHA + (long)bk*S_;
  float v = row[s] + ab[k];
  if (am[b*S_+s]==0) v = -10000.f;
  float mx = block_red_max(v, sh);
  float e = expf(v-mx);
  float sm = block_red_sum(e, sh);
  row[s] = e/sm;
}

__global__ __launch_bounds__(256) void k_pooled(const float* __restrict__ lh, float* __restrict__ ws)
{
  int k = blockIdx.x, b = blockIdx.y, t = threadIdx.x;
  __shared__ float al[S_];
  al[t] = ws[OFF_ALPHA + ((long)b*K_+k)*S_ + t];
  __syncthreads();
  const float* x = lh + (long)b*S_*H_;
  float a0=0,a1=0,a2=0;
  for (int s=0;s<S_;++s){
    float av = al[s];
    const float* xr = x + (long)s*H_;
    a0 += av*xr[t]; a1 += av*xr[t+256]; a2 += av*xr[t+512];
  }
  float* p = ws + OFF_POOLED + ((long)b*K_+k)*H_;
  p[t]=a0; p[t+256]=a1; p[t+512]=a2;
}

// ---------- GEMM: C[e,m,n] (+)= A[e,m,:] W[e,:,n], M=128, bias pre-init ----------
__global__ void k_biasinit(float* __restrict__ C, const float* __restrict__ bias,
                           int N, int ldc, long cbs)
{
  long idx = (long)blockIdx.x*256 + threadIdx.x;
  int n = (int)(idx % N);
  long r = idx / N;
  int m = (int)(r % 128);
  long e = r / 128;
  C[e*cbs + (long)m*ldc + n] = bias[e*N + n];
}

__global__ __launch_bounds__(256) void sgemm128(
    const float* __restrict__ A, int lda, long abs_,
    const float* __restrict__ W, long wbs,
    float* __restrict__ C, int ldc, long cbs,
    int N, int K, int KT)
{
  const float* Ae = A + (long)blockIdx.z*abs_;
  const float* We = W + (long)blockIdx.z*wbs;
  float* Ce = C + (long)blockIdx.z*cbs;
  int n0 = blockIdx.x*64;
  int kb = blockIdx.y*KT;
  int ke = min(K, kb+KT);
  __shared__ float As[32][132];
  __shared__ float Ws[32][68];
  int t = threadIdx.x;
  int tm = t>>4, tn = t&15;
  float acc[8][4];
  #pragma unroll
  for (int i=0;i<8;++i)
    #pragma unroll
    for (int j=0;j<4;++j) acc[i][j]=0.f;

  for (int k0=kb; k0<ke; k0+=32){
    #pragma unroll
    for (int r=0;r<8;++r){
      int idx = t + r*256;
      int bb = idx>>4, kk2 = idx&15;
      int k = k0 + kk2*2;
      float2 v = make_float2(0.f,0.f);
      if (k < ke) v = *(const float2*)(Ae + (long)bb*lda + k);
      As[kk2*2][bb]   = v.x;
      As[kk2*2+1][bb] = v.y;
    }
    #pragma unroll
    for (int r=0;r<4;++r){
      int idx = t + r*256;
      int kk = idx>>5, n2 = idx&31;
      int k = k0 + kk;
      float2 v = make_float2(0.f,0.f);
      if (k < ke) v = *(const float2*)(We + (long)k*N + n0 + n2*2);
      Ws[kk][n2*2]   = v.x;
      Ws[kk][n2*2+1] = v.y;
    }
    __syncthreads();
    #pragma unroll 8
    for (int kk=0;kk<32;++kk){
      float4 alo = *(const float4*)&As[kk][tm*8];
      float4 ahi = *(const float4*)&As[kk][tm*8+4];
      float4 wv  = *(const float4*)&Ws[kk][tn*4];
      float am_[8] = {alo.x,alo.y,alo.z,alo.w,ahi.x,ahi.y,ahi.z,ahi.w};
      float wn[4]  = {wv.x,wv.y,wv.z,wv.w};
      #pragma unroll
      for (int i=0;i<8;++i)
        #pragma unroll
        for (int j=0;j<4;++j) acc[i][j] += am_[i]*wn[j];
    }
    __syncthreads();
  }
  #pragma unroll
  for (int i=0;i<8;++i){
    float* cr = Ce + (long)(tm*8+i)*ldc + n0 + tn*4;
    #pragma unroll
    for (int j=0;j<4;++j) atomicAdd(&cr[j], acc[i][j]);
  }
}

// ---------- gelu + LayerNorm over contiguous rows ----------
__global__ void k_gln(float* __restrict__ X, int D,
                      const float* __restrict__ gam, const float* __restrict__ bet, int gmod)
{
  __shared__ float sh[4];
  long row = blockIdx.x;
  float* x = X + row*D;
  const float* g  = gam + (row % gmod)*D;
  const float* bb = bet + (row % gmod)*D;
  float s=0.f, s2=0.f;
  for (int i=threadIdx.x;i<D;i+=256){
    float gv = gelu_f(x[i]);
    x[i]=gv; s+=gv; s2+=gv*gv;
  }
  s  = block_red_sum(s, sh);
  s2 = block_red_sum(s2, sh);
  float m = s/D;
  float var = s2/D - m*m;
  float rs = rsqrtf(var + 1e-5f);
  for (int i=threadIdx.x;i<D;i+=256)
    x[i] = (x[i]-m)*rs*g[i] + bb[i];
}

__global__ void k_aux(const float* __restrict__ ws, const float* __restrict__ auxw,
                      const float* __restrict__ auxb, float* __restrict__ out)
{
  __shared__ float sh[4];
  int row = blockIdx.x; int k = row%K_;
  const float* z = ws + OFF_Z + (long)row*512;
  int t = threadIdx.x;
  float v = z[t]*auxw[k*512+t] + z[t+256]*auxw[k*512+t+256];
  v = block_red_sum(v, sh);
  if (t==0) out[OUT_AUX + row] = v + auxb[k];
}

__global__ void k_rin(float* __restrict__ ws, const float* __restrict__ out,
    const float* __restrict__ cat, const float* __restrict__ src,
    const float* __restrict__ pw, const float* __restrict__ pb,
    const float* __restrict__ pt, const int* __restrict__ cid, const int* __restrict__ sid)
{
  int b = blockIdx.x, t = threadIdx.x;
  const float* zb = out + OUT_ZB + (long)b*3846;
  float* r = ws + OFF_RIN + (long)b*3942;
  for (int i=t;i<3846;i+=256) r[i]=zb[i];
  if (t<32){
    r[3846+t] = cat[cid[b]*32+t];
    r[3878+t] = src[sid[b]*32+t];
    float a = pb[t];
    #pragma unroll
    for (int i=0;i<6;++i) a += pt[b*6+i]*pw[i*32+t];
    r[3910+t] = a;
  }
}

__global__ void k_router(float* __restrict__ ws, const float* __restrict__ w2,
    const float* __restrict__ b2, float* __restrict__ out)
{
  int b = blockIdx.x, lane = threadIdx.x;
  const float* rh = ws + OFF_RH + (long)b*512;
  float a[6]={0,0,0,0,0,0};
  for (int i=lane;i<512;i+=64){
    float x = rh[i];
    #pragma unroll
    for (int k=0;k<6;++k) a[k] += x*w2[i*6+k];
  }
  #pragma unroll
  for (int o=32;o;o>>=1){
    #pragma unroll
    for (int k=0;k<6;++k) a[k] += __shfl_down(a[k],o);
  }
  if (lane==0){
    float lg[6]; float mx=-1e30f;
    #pragma unroll
    for (int k=0;k<6;++k){ lg[k]=a[k]+b2[k]; mx=fmaxf(mx,lg[k]); }
    float e[6]; float s=0.f;
    #pragma unroll
    for (int k=0;k<6;++k){ e[k]=expf(lg[k]-mx); s+=e[k]; }
    #pragma unroll
    for (int k=0;k<6;++k){
      out[OUT_RL + b*6+k] = lg[k];
      float rwv = e[k]/s;
      out[OUT_RW + b*6+k] = rwv;
      ws[OFF_RWW + b*6+k] = rwv;
    }
  }
}

__global__ void k_cbuild(float* __restrict__ ws, const float* __restrict__ out,
    const float* __restrict__ g, const float* __restrict__ bb)
{
  __shared__ float sh[4];
  int b = blockIdx.x, t = threadIdx.x;
  const float* zb = out + OUT_ZB + (long)b*3846;
  const float* Zb = ws + OFF_Z + (long)b*3072;
  const float* rw = ws + OFF_RWW + b*6;
  float* c = ws + OFF_C + (long)b*6918;
  float s=0.f, s2=0.f;
  for (int i=t;i<6918;i+=256){
    float v;
    if (i<3846) v = zb[i];
    else { int j=i-3846; v = Zb[j]*rw[j>>9]; }
    c[i]=v; s+=v; s2+=v*v;
  }
  s  = block_red_sum(s,sh);
  s2 = block_red_sum(s2,sh);
  float m = s/6918.f;
  float var = s2/6918.f - m*m;
  float rs = rsqrtf(var+1e-5f);
  for (int i=t;i<6918;i+=256) c[i] = (c[i]-m)*rs*g[i]+bb[i];
}

__global__ void k_gelu(float* __restrict__ x, long n){
  long i = (long)blockIdx.x*256 + threadIdx.x;
  if (i<n) x[i] = gelu_f(x[i]);
}

__global__ void k_logits(const float* __restrict__ ws, const float* __restrict__ w3,
    const float* __restrict__ b3, float* __restrict__ out)
{
  __shared__ float sh[4];
  int b = blockIdx.x, t = threadIdx.x;
  float v = ws[OFF_C2 + b*256 + t]*w3[t];
  v = block_red_sum(v,sh);
  if (t==0) out[b] = v + b3[0];
}

extern "C" void kernel_launch(void* const* d_in, const int* in_sizes, int n_in,
                              void* d_out, int out_size, void* d_ws, size_t ws_size,
                              hipStream_t stream) {
  const float* attn_w = (const float*)d_in[0];
  const float* attn_b = (const float*)d_in[1];
  const float* ad_w1  = (const float*)d_in[2];
  const float* ad_b1  = (const float*)d_in[3];
  const float* ad_lng = (const float*)d_in[4];
  const float* ad_lnb = (const float*)d_in[5];
  const float* ad_w2  = (const float*)d_in[6];
  const float* ad_b2  = (const float*)d_in[7];
  const float* aux_w  = (const float*)d_in[8];
  const float* aux_b  = (const float*)d_in[9];
  const float* cat_emb= (const float*)d_in[10];
  const float* src_emb= (const float*)d_in[11];
  const float* pat_w  = (const float*)d_in[12];
  const float* pat_b  = (const float*)d_in[13];
  const float* r_w1   = (const float*)d_in[14];
  const float* r_b1   = (const float*)d_in[15];
  const float* r_lng  = (const float*)d_in[16];
  const float* r_lnb  = (const float*)d_in[17];
  const float* r_w2   = (const float*)d_in[18];
  const float* r_b2   = (const float*)d_in[19];
  const float* cls_lng= (const float*)d_in[20];
  const float* cls_lnb= (const float*)d_in[21];
  const float* cls_w1 = (const float*)d_in[22];
  const float* cls_b1 = (const float*)d_in[23];
  const float* cls_w2 = (const float*)d_in[24];
  const float* cls_b2 = (const float*)d_in[25];
  const float* cls_w3 = (const float*)d_in[26];
  const float* cls_b3 = (const float*)d_in[27];
  const float* layer_w= (const float*)d_in[28];
  const float* hidden4= (const float*)d_in[29];
  const float* lh     = (const float*)d_in[30];
  const float* pt     = (const float*)d_in[31];
  const int* cid      = (const int*)d_in[33];
  const int* sid      = (const int*)d_in[34];
  const int* ids      = (const int*)d_in[35];
  const int* am       = (const int*)d_in[36];
  float* out = (float*)d_out;
  float* ws  = (float*)d_ws;

  // zero the u/v accumulators (atomic targets)
  hipMemsetAsync(ws + OFF_UACC, 0, (size_t)2*B_*H_*sizeof(float), stream);

  k_prep<<<B_, 64, 0, stream>>>(ids, am, layer_w, ws);
  k_pool<<<dim3(3,16,B_), 256, 0, stream>>>(hidden4, ws);
  k_zbase<<<B_, 768, 0, stream>>>(ws, out, lh, pt);

  k_scores<<<B_*S_/4, 256, 0, stream>>>(lh, attn_w, ws);
  k_softmax<<<B_*K_, 256, 0, stream>>>(ws, attn_b, am);
  k_pooled<<<dim3(K_,B_), 256, 0, stream>>>(lh, ws);

  // adapter layer 1: (B,K,768) x (K,768,768)
  k_biasinit<<<(K_*B_*768)/256, 256, 0, stream>>>(ws+OFF_H1, ad_b1, 768, 4608, 768);
  sgemm128<<<dim3(12,3,K_), 256, 0, stream>>>(ws+OFF_POOLED, 4608, 768, ad_w1, 589824,
                                              ws+OFF_H1, 4608, 768, 768, 768, 256);
  k_gln<<<B_*K_, 256, 0, stream>>>(ws+OFF_H1, 768, ad_lng, ad_lnb, K_);

  // adapter layer 2: (B,K,768) x (K,768,512)
  k_biasinit<<<(K_*B_*512)/256, 256, 0, stream>>>(ws+OFF_Z, ad_b2, 512, 3072, 512);
  sgemm128<<<dim3(8,3,K_), 256, 0, stream>>>(ws+OFF_H1, 4608, 768, ad_w2, 393216,
                                             ws+OFF_Z, 3072, 512, 512, 768, 256);
  k_aux<<<B_*K_, 256, 0, stream>>>(ws, aux_w, aux_b, out);

  // router
  k_rin<<<B_, 256, 0, stream>>>(ws, out, cat_emb, src_emb, pat_w, pat_b, pt, cid, sid);
  k_biasinit<<<(B_*512)/256, 256, 0, stream>>>(ws+OFF_RH, r_b1, 512, 512, 0);
  sgemm128<<<dim3(8,16,1), 256, 0, stream>>>(ws+OFF_RIN, 3942, 0, r_w1, 0,
                                             ws+OFF_RH, 512, 0, 512, 3942, 256);
  k_gln<<<B_, 256, 0, stream>>>(ws+OFF_RH, 512, r_lng, r_lnb, 1);
  k_router<<<B_, 64, 0, stream>>>(ws, r_w2, r_b2, out);

  // classifier
  k_cbuild<<<B_, 256, 0, stream>>>(ws, out, cls_lng, cls_lnb);
  k_biasinit<<<(B_*1024)/256, 256, 0, stream>>>(ws+OFF_C1, cls_b1, 1024, 1024, 0);
  sgemm128<<<dim3(16,14,1), 256, 0, stream>>>(ws+OFF_C, 6918, 0, cls_w1, 0,
                                              ws+OFF_C1, 1024, 0, 1024, 6918, 512);
  k_gelu<<<(B_*1024)/256, 256, 0, stream>>>(ws+OFF_C1, (long)B_*1024);
  k_biasinit<<<(B_*256)/256, 256, 0, stream>>>(ws+OFF_C2, cls_b2, 256, 256, 0);
  sgemm128<<<dim3(4,8,1), 256, 0, stream>>>(ws+OFF_C1, 1024, 0, cls_w2, 0,
                                            ws+OFF_C2, 256, 0, 256, 1024, 128);
  k_gelu<<<(B_*256)/256, 256, 0, stream>>>(ws+OFF_C2, (long)B_*256);
  k_logits<<<B_, 256, 0, stream>>>(ws, cls_w3, cls_b3, out);
}